// Round 4
// baseline (808.762 us; speedup 1.0000x reference)
//
#include <hip/hip_runtime.h>
#include <cstdint>
#include <cstddef>

#define D_DIM 256
#define K_CODES 4096
#define N_ROWS 16384
#define TILE 128
#define BK 16
#define NORM_ROWS_PER_BLK 32

// ---- numpy-pairwise sum of squares of a 128-float block (fp32, no contraction) ----
// Mirrors numpy's pairwise_sum base case (PW_BLOCKSIZE=128): 8 strided
// accumulators r[j] += s[i+j], combine ((r0+r1)+(r2+r3))+((r4+r5)+(r6+r7)),
// where s[k] = fl32(a[k]*a[k]) is rounded BEFORE the add (hence __fmul_rn/__fadd_rn
// to defeat -ffp-contract=fast).
__device__ __forceinline__ float np_sumsq_128(const float* __restrict__ a)
{
    float r[8];
    #pragma unroll
    for (int j = 0; j < 8; ++j) r[j] = __fmul_rn(a[j], a[j]);
    #pragma unroll
    for (int i = 8; i < 128; i += 8)
        #pragma unroll
        for (int j = 0; j < 8; ++j)
            r[j] = __fadd_rn(r[j], __fmul_rn(a[i + j], a[i + j]));
    return __fadd_rn(__fadd_rn(__fadd_rn(r[0], r[1]), __fadd_rn(r[2], r[3])),
                     __fadd_rn(__fadd_rn(r[4], r[5]), __fadd_rn(r[6], r[7])));
}

// ---- row L2-normalize replicating np.linalg.norm + division ----
// 256 threads handle 32 rows: coalesced load to LDS, 32 threads compute norms
// with numpy's exact summation order (256 = 128-block + 128-block, one final add),
// sqrt correctly rounded via double, then all threads write v / max(norm,1e-12).
__global__ __launch_bounds__(256) void norm_rows_np_kernel(
    const float* __restrict__ src, float* __restrict__ dst)
{
    __shared__ float lds[NORM_ROWS_PER_BLK * D_DIM];
    __shared__ float nrm[NORM_ROWS_PER_BLK];
    const int tid = threadIdx.x;
    const size_t base = (size_t)blockIdx.x * NORM_ROWS_PER_BLK * D_DIM;

    #pragma unroll
    for (int i = 0; i < NORM_ROWS_PER_BLK; ++i)
        lds[i * 256 + tid] = src[base + i * 256 + tid];
    __syncthreads();

    if (tid < NORM_ROWS_PER_BLK) {
        const float* row = &lds[tid * D_DIM];
        const float tot = __fadd_rn(np_sumsq_128(row), np_sumsq_128(row + 128));
        const float n = (float)sqrt((double)tot);   // correctly-rounded fp32 sqrt
        nrm[tid] = fmaxf(n, 1e-12f);
    }
    __syncthreads();

    #pragma unroll
    for (int i = 0; i < NORM_ROWS_PER_BLK; ++i) {
        const int e = i * 256 + tid;
        dst[base + e] = lds[e] / nrm[i];            // division, like the ref
    }
}

// ---------------- fp32 NT GEMM: C[N,K] = A[N,D] * B[K,D]^T ----------------
// 128x128 tile, BK=16, 256 threads, 8x8 microtile.
// Accumulation: strictly sequential k=0..255, single fp32 fma accumulator per
// element — same order/rounding as a BLAS sgemm micro-kernel.
__global__ __launch_bounds__(256) void gemm_nt_kernel(
    const float* __restrict__ A, const float* __restrict__ B, float* __restrict__ C)
{
    __shared__ float As[BK][TILE + 4];
    __shared__ float Bs[BK][TILE + 4];
    const int tid = threadIdx.x;
    const int tx = tid & 15;        // -> n
    const int ty = tid >> 4;        // -> m
    const int bm = blockIdx.y * TILE;
    const int bn = blockIdx.x * TILE;
    const int lrow = tid >> 2;      // 0..63
    const int lcol = (tid & 3) << 2;// 0,4,8,12

    float acc[8][8];
    #pragma unroll
    for (int i = 0; i < 8; ++i)
        #pragma unroll
        for (int j = 0; j < 8; ++j) acc[i][j] = 0.0f;

    for (int k0 = 0; k0 < D_DIM; k0 += BK) {
        const float4 a0 = *(const float4*)&A[(size_t)(bm + lrow)      * D_DIM + k0 + lcol];
        const float4 a1 = *(const float4*)&A[(size_t)(bm + lrow + 64) * D_DIM + k0 + lcol];
        const float4 b0 = *(const float4*)&B[(size_t)(bn + lrow)      * D_DIM + k0 + lcol];
        const float4 b1 = *(const float4*)&B[(size_t)(bn + lrow + 64) * D_DIM + k0 + lcol];
        __syncthreads();
        As[lcol + 0][lrow] = a0.x; As[lcol + 1][lrow] = a0.y;
        As[lcol + 2][lrow] = a0.z; As[lcol + 3][lrow] = a0.w;
        As[lcol + 0][lrow + 64] = a1.x; As[lcol + 1][lrow + 64] = a1.y;
        As[lcol + 2][lrow + 64] = a1.z; As[lcol + 3][lrow + 64] = a1.w;
        Bs[lcol + 0][lrow] = b0.x; Bs[lcol + 1][lrow] = b0.y;
        Bs[lcol + 2][lrow] = b0.z; Bs[lcol + 3][lrow] = b0.w;
        Bs[lcol + 0][lrow + 64] = b1.x; Bs[lcol + 1][lrow + 64] = b1.y;
        Bs[lcol + 2][lrow + 64] = b1.z; Bs[lcol + 3][lrow + 64] = b1.w;
        __syncthreads();
        #pragma unroll
        for (int kk = 0; kk < BK; ++kk) {
            float a[8], b[8];
            *(float4*)&a[0] = *(const float4*)&As[kk][ty * 8];
            *(float4*)&a[4] = *(const float4*)&As[kk][ty * 8 + 4];
            *(float4*)&b[0] = *(const float4*)&Bs[kk][tx * 8];
            *(float4*)&b[4] = *(const float4*)&Bs[kk][tx * 8 + 4];
            #pragma unroll
            for (int i = 0; i < 8; ++i)
                #pragma unroll
                for (int j = 0; j < 8; ++j)
                    acc[i][j] = fmaf(a[i], b[j], acc[i][j]);
        }
    }
    #pragma unroll
    for (int i = 0; i < 8; ++i) {
        const size_t off = (size_t)(bm + ty * 8 + i) * K_CODES + bn + tx * 8;
        *(float4*)&C[off]     = make_float4(acc[i][0], acc[i][1], acc[i][2], acc[i][3]);
        *(float4*)&C[off + 4] = make_float4(acc[i][4], acc[i][5], acc[i][6], acc[i][7]);
    }
}

// ---------------- per-row: np.argmin over dist32, softmax, gather ----------------
// Selection: dist32_i = fl32(2 - 2*cos32_i) with cos32 the GEMM's fp32 values
// (same arithmetic as the np reference's sgemm). argmin with FIRST-INDEX
// tie-break, exactly like np.argmin. No higher-precision override.
__global__ __launch_bounds__(256) void rowpass_kernel(
    float* __restrict__ P,            // [N,K] in: cos, out: soft_probs (in place)
    const float* __restrict__ cbn,    // [K,D] normalized codebook
    float* __restrict__ xq,           // [N,D] in: x_n, out: quantized (same region)
    float* __restrict__ idx_out,      // [N] (float)
    float* __restrict__ counts,       // [K]
    float* __restrict__ rowloss)      // [N]
{
    const int row = blockIdx.x;
    const int t = threadIdx.x;
    float4* rp = (float4*)(P + (size_t)row * K_CODES);

    float vals[16];
    #pragma unroll
    for (int j = 0; j < 4; ++j) {
        const float4 v = rp[j * 256 + t];
        vals[j * 4 + 0] = v.x; vals[j * 4 + 1] = v.y;
        vals[j * 4 + 2] = v.z; vals[j * 4 + 3] = v.w;
    }

    // ---- argmin over dist32 with first-index tie-break ----
    float bd = 3.402823466e+38f;
    int   bi = 0x7fffffff;
    float m = -1e30f;                  // also track max cos for softmax
    #pragma unroll
    for (int i = 0; i < 16; ++i) {
        const float d = 2.0f - 2.0f * vals[i];   // 2*c exact => single rounding
        const int idx = ((i >> 2) * 256 + t) * 4 + (i & 3);  // increasing in i
        if (d < bd) { bd = d; bi = idx; }        // strict < keeps first index
        m = fmaxf(m, vals[i]);
    }
    #pragma unroll
    for (int off = 32; off > 0; off >>= 1) {
        const float od = __shfl_down(bd, off);
        const int   oi = __shfl_down(bi, off);
        if (od < bd || (od == bd && oi < bi)) { bd = od; bi = oi; }
        m = fmaxf(m, __shfl_down(m, off));
    }
    __shared__ float sf[4];
    __shared__ float sbd[4];
    __shared__ int   sbi[4];
    if ((t & 63) == 0) { sf[t >> 6] = m; sbd[t >> 6] = bd; sbi[t >> 6] = bi; }
    __syncthreads();
    const float M = fmaxf(fmaxf(sf[0], sf[1]), fmaxf(sf[2], sf[3]));
    float fb = sbd[0]; int besti = sbi[0];
    #pragma unroll
    for (int w = 1; w < 4; ++w) {
        if (sbd[w] < fb || (sbd[w] == fb && sbi[w] < besti)) { fb = sbd[w]; besti = sbi[w]; }
    }

    const float xv = xq[(size_t)row * D_DIM + t];   // x_n element for this thread
    __syncthreads();

    // softmax: p_i = exp(20*(cos_i - M)) / sum   (TEMP=0.1, dist=2-2cos)
    float esum = 0.0f;
    #pragma unroll
    for (int i = 0; i < 16; ++i) {
        vals[i] = __expf(20.0f * (vals[i] - M));
        esum += vals[i];
    }
    #pragma unroll
    for (int off = 32; off > 0; off >>= 1) esum += __shfl_down(esum, off);
    if ((t & 63) == 0) sf[t >> 6] = esum;
    __syncthreads();
    const float inv = 1.0f / (sf[0] + sf[1] + sf[2] + sf[3]);
    #pragma unroll
    for (int j = 0; j < 4; ++j) {
        rp[j * 256 + t] = make_float4(vals[j * 4 + 0] * inv, vals[j * 4 + 1] * inv,
                                      vals[j * 4 + 2] * inv, vals[j * 4 + 3] * inv);
    }

    // gather quantized row, per-row commitment loss
    const float q = cbn[(size_t)besti * D_DIM + t];
    xq[(size_t)row * D_DIM + t] = q;    // xv already read; safe overwrite
    const float dd = q - xv;
    float ls = dd * dd;
    #pragma unroll
    for (int off = 32; off > 0; off >>= 1) ls += __shfl_down(ls, off);
    __syncthreads();
    if ((t & 63) == 0) sf[t >> 6] = ls;
    __syncthreads();
    if (t == 0) {
        rowloss[row] = sf[0] + sf[1] + sf[2] + sf[3];
        idx_out[row] = (float)besti;
        atomicAdd(&counts[besti], 1.0f);
    }
}

// ---------------- finalize: vq_loss scalar + perplexity ----------------
__global__ __launch_bounds__(256) void finalize_kernel(
    const float* __restrict__ rowloss, const float* __restrict__ counts,
    float* __restrict__ out_loss, float* __restrict__ out_ppl)
{
    const int t = threadIdx.x;
    float s = 0.0f;
    for (int i = t; i < N_ROWS; i += 256) s += rowloss[i];
    float e = 0.0f;
    for (int i = t; i < K_CODES; i += 256) {
        const float avg = counts[i] * (1.0f / (float)N_ROWS);
        e += avg * logf(avg + 1e-10f);
    }
    #pragma unroll
    for (int off = 32; off > 0; off >>= 1) {
        s += __shfl_down(s, off);
        e += __shfl_down(e, off);
    }
    __shared__ float sf[4], se[4];
    if ((t & 63) == 0) { sf[t >> 6] = s; se[t >> 6] = e; }
    __syncthreads();
    if (t == 0) {
        out_loss[0] = 0.25f * (sf[0] + sf[1] + sf[2] + sf[3]) /
                      ((float)N_ROWS * (float)D_DIM);
        out_ppl[0] = expf(-(se[0] + se[1] + se[2] + se[3]));
    }
}

extern "C" void kernel_launch(void* const* d_in, const int* in_sizes, int n_in,
                              void* d_out, int out_size, void* d_ws, size_t ws_size,
                              hipStream_t stream) {
    const float* inputs   = (const float*)d_in[0];   // [N, D] raw
    const float* codebook = (const float*)d_in[1];   // [K, D] raw
    float* out = (float*)d_out;

    // output layout (flat, return order)
    float* vq_loss = out;                                   // 1
    float* quant   = out + 1;                               // N*D (also x_n scratch)
    float* probs   = quant + (size_t)N_ROWS * D_DIM;        // N*K
    float* ppl     = probs + (size_t)N_ROWS * K_CODES;      // 1
    float* idxout  = ppl + 1;                               // N

    // workspace layout
    float* cbn     = (float*)d_ws;                          // K*D
    float* counts  = cbn + (size_t)K_CODES * D_DIM;         // K
    float* rowloss = counts + K_CODES;                      // N

    hipMemsetAsync(counts, 0, K_CODES * sizeof(float), stream);
    norm_rows_np_kernel<<<K_CODES / NORM_ROWS_PER_BLK, 256, 0, stream>>>(codebook, cbn);
    norm_rows_np_kernel<<<N_ROWS / NORM_ROWS_PER_BLK, 256, 0, stream>>>(inputs, quant);
    gemm_nt_kernel<<<dim3(K_CODES / TILE, N_ROWS / TILE), 256, 0, stream>>>(quant, cbn, probs);
    rowpass_kernel<<<N_ROWS, 256, 0, stream>>>(probs, cbn,
                                               quant, idxout, counts, rowloss);
    finalize_kernel<<<1, 256, 0, stream>>>(rowloss, counts, vq_loss, ppl);
}